// Round 19
// baseline (126.089 us; speedup 1.0000x reference)
//
#include <hip/hip_runtime.h>
#include <hip/hip_bf16.h>

// Windowed MHA, B=16 C=128 H=W=128, WINDOW=64, heads=4, d=32.
// R19 = R18 per-wave pipeline, but 512-thread blocks covering TWO windows
// (grid 2048): waves 0-3 = window A heads 0-3, waves 4-7 = window B.
// Tests the observed ~2-blocks/CU residency cap: if blocks/CU is capped,
// waves/CU scales with block size -> 2x resident waves.
// Staging is direct load->pack->write (transient regs) -- NOT R16's
// register prefetch that spilled. Per-wave code byte-identical to R18.

typedef __attribute__((ext_vector_type(8))) short bf16x8;
typedef __attribute__((ext_vector_type(4))) short bf16x4;
typedef __attribute__((ext_vector_type(4))) float f32x4;

#define MFMA32(A, B, C) __builtin_amdgcn_mfma_f32_16x16x32_bf16((A), (B), (C), 0, 0, 0)
#define MFMA16(A, B, C) __builtin_amdgcn_mfma_f32_16x16x16bf16_1k((A), (B), (C), 0, 0, 0)

__device__ __forceinline__ ushort f2bf(float f) {
    __hip_bfloat16 h = __float2bfloat16(f);       // RNE
    ushort u; __builtin_memcpy(&u, &h, 2); return u;
}
__device__ __forceinline__ unsigned pk2(float a, float b) {
    __hip_bfloat162 h = __float22bfloat162_rn(make_float2(a, b));  // lo=a, hi=b
    unsigned u; __builtin_memcpy(&u, &h, 4); return u;
}
__device__ __forceinline__ bf16x4 pk4(float a, float b, float c, float d) {
    uint2 u; u.x = pk2(a, b); u.y = pk2(c, d);
    bf16x4 r; __builtin_memcpy(&r, &u, 8); return r;
}
// 256B-row tile (sX): row bits 0-3 ^ bits 4-5 -> byte bits 4-7.
__device__ __forceinline__ int fsw(int row) { return ((row ^ (row >> 4)) & 15) << 4; }

__global__ void wconv(const float* __restrict__ Wq, const float* __restrict__ Wk,
                      const float* __restrict__ Wv, ushort* __restrict__ out) {
    int i = blockIdx.x * 256 + threadIdx.x;        // 16384 per matrix
    out[i]         = f2bf(Wq[i]);
    out[16384 + i] = f2bf(Wk[i]);
    out[32768 + i] = f2bf(Wv[i]);
}

__global__ __launch_bounds__(512, 2)
void attn_win(const float* __restrict__ x, const ushort* __restrict__ wbf,
              const float* __restrict__ bq, const float* __restrict__ bk,
              const float* __restrict__ bv, const float* __restrict__ Bb,
              float* __restrict__ out) {
    __shared__ __align__(16) char sX[2][16384];

    const int tid = threadIdx.x;
    const int wid = tid >> 6;        // 0..7
    const int wi = wid >> 2;         // window within block (0..1)
    const int w = wid & 3;           // head
    const int l = tid & 63;
    const int lr = l & 15;
    const int lg = (l >> 4) & 3;
    const int blk = blockIdx.x;      // 2048 blocks; windows 2blk, 2blk+1
    const int gw0 = 2 * blk;         // even -> both windows share batch b
    const long xbase0 = (long)(gw0 >> 8) * 128 * 16384 + (long)(gw0 & 255) * 64;

    // ---- stage BOTH windows: direct load -> pack -> ds_write (transient) ----
    #pragma unroll
    for (int it = 0; it < 2; ++it) {
        int idx = it * 512 + tid;            // 1024 items: wi x 32cq x 16t4
        int swi = idx >> 9, rem = idx & 511;
        int cq = rem >> 4, t4 = rem & 15;
        const float* px = x + xbase0 + swi * 64 + (long)(4 * cq) * 16384 + t4 * 4;
        float4 v0 = *(const float4*)(px);
        float4 v1 = *(const float4*)(px + 16384);
        float4 v2 = *(const float4*)(px + 32768);
        float4 v3 = *(const float4*)(px + 49152);
        float a0[4] = {v0.x, v0.y, v0.z, v0.w};
        float a1[4] = {v1.x, v1.y, v1.z, v1.w};
        float a2[4] = {v2.x, v2.y, v2.z, v2.w};
        float a3[4] = {v3.x, v3.y, v3.z, v3.w};
        #pragma unroll
        for (int jj = 0; jj < 4; ++jj) {
            int t = t4 * 4 + jj;
            uint2 pk;
            pk.x = pk2(a0[jj], a1[jj]);
            pk.y = pk2(a2[jj], a3[jj]);
            *(uint2*)(&sX[swi][0] + t * 256 + ((8 * cq) ^ fsw(t))) = pk;
        }
    }
    __syncthreads();   // THE ONLY BARRIER

    const char* sXw = &sX[wi][0];
    const long xb = xbase0 + wi * 64;

    // ---- Q,K projections FUSED (W.X^T), K=32 MFMA, b128 loads ----
    // D[och 4lg+r][tok lr] per (tn,tm) -> pk4 -> K=16 fragment, k-slice tn.
    bf16x4 fQ[4][2], fK[4][2];   // [tm tok-tile][tn och-slice]
    {
        f32x4 accQ[2][4], accK[2][4];   // [tn][tm]
        #pragma unroll
        for (int tn = 0; tn < 2; ++tn) {
            float4 bbq = *(const float4*)(bq + 32 * w + 16 * tn + 4 * lg);
            float4 bbk = *(const float4*)(bk + 32 * w + 16 * tn + 4 * lg);
            #pragma unroll
            for (int tm = 0; tm < 4; ++tm) {
                accQ[tn][tm] = (f32x4){bbq.x, bbq.y, bbq.z, bbq.w};
                accK[tn][tm] = (f32x4){bbk.x, bbk.y, bbk.z, bbk.w};
            }
        }
        #pragma unroll
        for (int kk = 0; kk < 4; ++kk) {
            bf16x8 aXk[4];
            #pragma unroll
            for (int tm = 0; tm < 4; ++tm) {
                int row = 16 * tm + lr;
                aXk[tm] = *(const bf16x8*)(sXw + row * 256
                              + (((8 * lg + 32 * kk) * 2) ^ fsw(row)));
            }
            bf16x8 bWq[2], bWk[2];
            #pragma unroll
            for (int tn = 0; tn < 2; ++tn) {
                int orow = (32 * w + 16 * tn + lr) * 128 + 8 * lg + 32 * kk;
                bWq[tn] = *(const bf16x8*)(wbf + orow);
                bWk[tn] = *(const bf16x8*)(wbf + 16384 + orow);
            }
            #pragma unroll
            for (int tn = 0; tn < 2; ++tn)
                #pragma unroll
                for (int tm = 0; tm < 4; ++tm) {
                    accQ[tn][tm] = MFMA32(bWq[tn], aXk[tm], accQ[tn][tm]);
                    accK[tn][tm] = MFMA32(bWk[tn], aXk[tm], accK[tn][tm]);
                }
        }
        #pragma unroll
        for (int tm = 0; tm < 4; ++tm)
            #pragma unroll
            for (int tn = 0; tn < 2; ++tn) {
                fQ[tm][tn] = pk4(accQ[tn][tm][0], accQ[tn][tm][1],
                                 accQ[tn][tm][2], accQ[tn][tm][3]);
                fK[tm][tn] = pk4(accK[tn][tm][0], accK[tn][tm][1],
                                 accK[tn][tm][2], accK[tn][tm][3]);
            }
    }

    // ---- V projection (X.W^T), K=32: D[tok 4lg+r][och lr] -> PV B-frags ----
    bf16x4 fV[4][2];   // [tmi key-slice][tn]
    {
        const ushort* wp = wbf + 32768;
        f32x4 accV[4][2];
        #pragma unroll
        for (int tn = 0; tn < 2; ++tn) {
            float bias = bv[32 * w + 16 * tn + lr];
            #pragma unroll
            for (int tmi = 0; tmi < 4; ++tmi)
                accV[tmi][tn] = (f32x4){bias, bias, bias, bias};
        }
        #pragma unroll
        for (int kk = 0; kk < 4; ++kk) {
            bf16x8 aXk[4];
            #pragma unroll
            for (int tmi = 0; tmi < 4; ++tmi) {
                int row = 16 * tmi + lr;
                aXk[tmi] = *(const bf16x8*)(sXw + row * 256
                               + (((8 * lg + 32 * kk) * 2) ^ fsw(row)));
            }
            bf16x8 bW[2];
            #pragma unroll
            for (int tn = 0; tn < 2; ++tn)
                bW[tn] = *(const bf16x8*)(wp + (32 * w + 16 * tn + lr) * 128 + 8 * lg + 32 * kk);
            #pragma unroll
            for (int tmi = 0; tmi < 4; ++tmi)
                #pragma unroll
                for (int tn = 0; tn < 2; ++tn)
                    accV[tmi][tn] = MFMA32(aXk[tmi], bW[tn], accV[tmi][tn]);
        }
        #pragma unroll
        for (int tmi = 0; tmi < 4; ++tmi)
            #pragma unroll
            for (int tn = 0; tn < 2; ++tn)
                fV[tmi][tn] = pk4(accV[tmi][tn][0], accV[tmi][tn][1],
                                  accV[tmi][tn][2], accV[tmi][tn][3]);
    }

    // ---- per-tmQ: scores^T = K=16 mfma(A=fK, B=fQ) -> softmax -> pack P ----
    const float scale = 0.17677669529663687f;   // 1/sqrt(32)
    const float L2E = 1.4426950408889634f;
    bf16x4 pP[4][4];   // [tmK][tmQ]
    #pragma unroll
    for (int tmQ = 0; tmQ < 4; ++tmQ) {
        f32x4 sc[4];
        #pragma unroll
        for (int tmK = 0; tmK < 4; ++tmK) {
            sc[tmK] = (f32x4){0.f, 0.f, 0.f, 0.f};
            sc[tmK] = MFMA16(fK[tmK][0], fQ[tmQ][0], sc[tmK]);
            sc[tmK] = MFMA16(fK[tmK][1], fQ[tmQ][1], sc[tmK]);
        }
        int q = 16 * tmQ + lr;
        float s = 0.f;
        #pragma unroll
        for (int tmK = 0; tmK < 4; ++tmK) {
            float4 bb = *(const float4*)(Bb + q * 64 + 16 * tmK + 4 * lg);
            float e0 = exp2f((sc[tmK][0] * scale + bb.x) * L2E);
            float e1 = exp2f((sc[tmK][1] * scale + bb.y) * L2E);
            float e2 = exp2f((sc[tmK][2] * scale + bb.z) * L2E);
            float e3 = exp2f((sc[tmK][3] * scale + bb.w) * L2E);
            sc[tmK][0] = e0; sc[tmK][1] = e1;
            sc[tmK][2] = e2; sc[tmK][3] = e3;
            s += (e0 + e1) + (e2 + e3);
        }
        s += __shfl_xor(s, 16);
        s += __shfl_xor(s, 32);
        float rs = 1.0f / s;
        #pragma unroll
        for (int tmK = 0; tmK < 4; ++tmK)
            pP[tmK][tmQ] = pk4(sc[tmK][0] * rs, sc[tmK][1] * rs,
                               sc[tmK][2] * rs, sc[tmK][3] * rs);
    }

    // ---- PV: K=16 mfma(A=pP, B=fV); D[q 4lg+r][d lr] ----
    f32x4 o[4][2];
    #pragma unroll
    for (int tmq = 0; tmq < 4; ++tmq)
        #pragma unroll
        for (int tn = 0; tn < 2; ++tn)
            o[tmq][tn] = (f32x4){0.f, 0.f, 0.f, 0.f};
    #pragma unroll
    for (int tmK = 0; tmK < 4; ++tmK)
        #pragma unroll
        for (int tmq = 0; tmq < 4; ++tmq)
            #pragma unroll
            for (int tn = 0; tn < 2; ++tn)
                o[tmq][tn] = MFMA16(pP[tmK][tmq], fV[tmK][tn], o[tmq][tn]);

    // ---- direct coalesced float4 stores (4 consecutive tokens per reg) ----
    #pragma unroll
    for (int tmq = 0; tmq < 4; ++tmq)
        #pragma unroll
        for (int tn = 0; tn < 2; ++tn) {
            int ch = 32 * w + 16 * tn + lr;
            int tok = 16 * tmq + 4 * lg;
            float4 ov;
            ov.x = o[tmq][tn][0];
            ov.y = o[tmq][tn][1];
            ov.z = o[tmq][tn][2];
            ov.w = o[tmq][tn][3];
            *(float4*)(out + xb + (long)ch * 16384 + tok) = ov;
        }
}

extern "C" void kernel_launch(void* const* d_in, const int* in_sizes, int n_in,
                              void* d_out, int out_size, void* d_ws, size_t ws_size,
                              hipStream_t stream) {
    const float* x  = (const float*)d_in[0];
    const float* Wq = (const float*)d_in[1];
    const float* bq = (const float*)d_in[2];
    const float* Wk = (const float*)d_in[3];
    const float* bk = (const float*)d_in[4];
    const float* Wv = (const float*)d_in[5];
    const float* bv = (const float*)d_in[6];
    const float* Bb = (const float*)d_in[7];
    float* out = (float*)d_out;
    ushort* wbf = (ushort*)d_ws;   // 3 x 128x128 bf16 = 96 KB

    wconv<<<64, 256, 0, stream>>>(Wq, Wk, Wv, wbf);
    attn_win<<<2048, 512, 0, stream>>>(x, wbf, bq, bk, bv, Bb, out);
}

// Round 20
// 111.489 us; speedup vs baseline: 1.1310x; 1.1310x over previous
//
#include <hip/hip_runtime.h>
#include <hip/hip_bf16.h>

// Windowed MHA, B=16 C=128 H=W=128, WINDOW=64, heads=4, d=32.
// R20 = R18 with ALL THREE projections fused into ONE kk loop:
//   - shared aXk LDS reads (32 -> 16 ds_read_b128 per wave)
//   - 24 independent MFMA accumulators per kk (max ILP on longest phase)
//   - 6 independent b128 weight loads issued per kk (latency hiding)
// Attention part unchanged (K=16 consuming projection D-layouts directly,
// zero shfl). One wave = one (window, head); 4096 x 256thr; ONE barrier.

typedef __attribute__((ext_vector_type(8))) short bf16x8;
typedef __attribute__((ext_vector_type(4))) short bf16x4;
typedef __attribute__((ext_vector_type(4))) float f32x4;

#define MFMA32(A, B, C) __builtin_amdgcn_mfma_f32_16x16x32_bf16((A), (B), (C), 0, 0, 0)
#define MFMA16(A, B, C) __builtin_amdgcn_mfma_f32_16x16x16bf16_1k((A), (B), (C), 0, 0, 0)

__device__ __forceinline__ ushort f2bf(float f) {
    __hip_bfloat16 h = __float2bfloat16(f);       // RNE
    ushort u; __builtin_memcpy(&u, &h, 2); return u;
}
__device__ __forceinline__ unsigned pk2(float a, float b) {
    __hip_bfloat162 h = __float22bfloat162_rn(make_float2(a, b));  // lo=a, hi=b
    unsigned u; __builtin_memcpy(&u, &h, 4); return u;
}
__device__ __forceinline__ bf16x4 pk4(float a, float b, float c, float d) {
    uint2 u; u.x = pk2(a, b); u.y = pk2(c, d);
    bf16x4 r; __builtin_memcpy(&r, &u, 8); return r;
}
// 256B-row tile (sX): row bits 0-3 ^ bits 4-5 -> byte bits 4-7.
__device__ __forceinline__ int fsw(int row) { return ((row ^ (row >> 4)) & 15) << 4; }

__global__ void wconv(const float* __restrict__ Wq, const float* __restrict__ Wk,
                      const float* __restrict__ Wv, ushort* __restrict__ out) {
    int i = blockIdx.x * 256 + threadIdx.x;        // 16384 per matrix
    out[i]         = f2bf(Wq[i]);
    out[16384 + i] = f2bf(Wk[i]);
    out[32768 + i] = f2bf(Wv[i]);
}

__global__ __launch_bounds__(256, 2)
void attn_win(const float* __restrict__ x, const ushort* __restrict__ wbf,
              const float* __restrict__ bq, const float* __restrict__ bk,
              const float* __restrict__ bv, const float* __restrict__ Bb,
              float* __restrict__ out) {
    __shared__ __align__(16) char sX[16384];   // the ONLY LDS tenant

    const int tid = threadIdx.x;
    const int w = tid >> 6;          // wave = head (0..3)
    const int l = tid & 63;
    const int lr = l & 15;
    const int lg = (l >> 4) & 3;
    const int blk = blockIdx.x;
    const int b = blk >> 8, n = blk & 255;
    const long xbase = (long)b * 128 * 16384 + n * 64;

    // ---- stage X: 4-channel quads -> packed uint2 ds_writes (2 per thread) ----
    #pragma unroll
    for (int it = 0; it < 2; ++it) {
        int idx = it * 256 + tid;            // 512 items: 32 cq x 16 t4
        int cq = idx >> 4, t4 = idx & 15;
        const float* px = x + xbase + (long)(4 * cq) * 16384 + t4 * 4;
        float4 v0 = *(const float4*)(px);
        float4 v1 = *(const float4*)(px + 16384);
        float4 v2 = *(const float4*)(px + 32768);
        float4 v3 = *(const float4*)(px + 49152);
        float a0[4] = {v0.x, v0.y, v0.z, v0.w};
        float a1[4] = {v1.x, v1.y, v1.z, v1.w};
        float a2[4] = {v2.x, v2.y, v2.z, v2.w};
        float a3[4] = {v3.x, v3.y, v3.z, v3.w};
        #pragma unroll
        for (int jj = 0; jj < 4; ++jj) {
            int t = t4 * 4 + jj;
            uint2 pk;
            pk.x = pk2(a0[jj], a1[jj]);
            pk.y = pk2(a2[jj], a3[jj]);
            *(uint2*)(sX + t * 256 + ((8 * cq) ^ fsw(t))) = pk;
        }
    }
    __syncthreads();   // THE ONLY BARRIER

    // ---- Q,K,V projections FULLY FUSED, K=32 MFMA, one kk loop ----
    // Q,K: W.X^T -> D[och 4lg+r][tok lr]  (A=W, B=X)
    // V:   X.W^T -> D[tok 4lg+r][och lr]  (A=X, B=W)
    bf16x4 fQ[4][2], fK[4][2];   // [tm tok-tile][tn och-slice] K=16 frags
    bf16x4 fV[4][2];             // [tmi key-slice][tn]
    {
        f32x4 accQ[2][4], accK[2][4], accV[4][2];
        #pragma unroll
        for (int tn = 0; tn < 2; ++tn) {
            float4 bbq = *(const float4*)(bq + 32 * w + 16 * tn + 4 * lg);
            float4 bbk = *(const float4*)(bk + 32 * w + 16 * tn + 4 * lg);
            float bvv = bv[32 * w + 16 * tn + lr];
            #pragma unroll
            for (int tm = 0; tm < 4; ++tm) {
                accQ[tn][tm] = (f32x4){bbq.x, bbq.y, bbq.z, bbq.w};
                accK[tn][tm] = (f32x4){bbk.x, bbk.y, bbk.z, bbk.w};
                accV[tm][tn] = (f32x4){bvv, bvv, bvv, bvv};
            }
        }
        #pragma unroll
        for (int kk = 0; kk < 4; ++kk) {
            bf16x8 aXk[4];
            #pragma unroll
            for (int tm = 0; tm < 4; ++tm) {
                int row = 16 * tm + lr;
                aXk[tm] = *(const bf16x8*)(sX + row * 256
                              + (((8 * lg + 32 * kk) * 2) ^ fsw(row)));
            }
            bf16x8 bWq[2], bWk[2], bWv[2];
            #pragma unroll
            for (int tn = 0; tn < 2; ++tn) {
                int orow = (32 * w + 16 * tn + lr) * 128 + 8 * lg + 32 * kk;
                bWq[tn] = *(const bf16x8*)(wbf + orow);
                bWk[tn] = *(const bf16x8*)(wbf + 16384 + orow);
                bWv[tn] = *(const bf16x8*)(wbf + 32768 + orow);
            }
            #pragma unroll
            for (int tn = 0; tn < 2; ++tn)
                #pragma unroll
                for (int tm = 0; tm < 4; ++tm) {
                    accQ[tn][tm] = MFMA32(bWq[tn], aXk[tm], accQ[tn][tm]);
                    accK[tn][tm] = MFMA32(bWk[tn], aXk[tm], accK[tn][tm]);
                    accV[tm][tn] = MFMA32(aXk[tm], bWv[tn], accV[tm][tn]);
                }
        }
        #pragma unroll
        for (int tm = 0; tm < 4; ++tm)
            #pragma unroll
            for (int tn = 0; tn < 2; ++tn) {
                fQ[tm][tn] = pk4(accQ[tn][tm][0], accQ[tn][tm][1],
                                 accQ[tn][tm][2], accQ[tn][tm][3]);
                fK[tm][tn] = pk4(accK[tn][tm][0], accK[tn][tm][1],
                                 accK[tn][tm][2], accK[tn][tm][3]);
                fV[tm][tn] = pk4(accV[tm][tn][0], accV[tm][tn][1],
                                 accV[tm][tn][2], accV[tm][tn][3]);
            }
    }

    // ---- per-tmQ: scores^T = K=16 mfma(A=fK, B=fQ) -> softmax -> pack P ----
    // D[k 16tmK+4lg+r][q 16tmQ+lr]; P pack is directly the PV A-fragment.
    const float scale = 0.17677669529663687f;   // 1/sqrt(32)
    const float L2E = 1.4426950408889634f;
    bf16x4 pP[4][4];   // [tmK][tmQ]
    #pragma unroll
    for (int tmQ = 0; tmQ < 4; ++tmQ) {
        f32x4 sc[4];
        #pragma unroll
        for (int tmK = 0; tmK < 4; ++tmK) {
            sc[tmK] = (f32x4){0.f, 0.f, 0.f, 0.f};
            sc[tmK] = MFMA16(fK[tmK][0], fQ[tmQ][0], sc[tmK]);
            sc[tmK] = MFMA16(fK[tmK][1], fQ[tmQ][1], sc[tmK]);
        }
        int q = 16 * tmQ + lr;
        float s = 0.f;
        #pragma unroll
        for (int tmK = 0; tmK < 4; ++tmK) {
            float4 bb = *(const float4*)(Bb + q * 64 + 16 * tmK + 4 * lg);
            float e0 = exp2f((sc[tmK][0] * scale + bb.x) * L2E);
            float e1 = exp2f((sc[tmK][1] * scale + bb.y) * L2E);
            float e2 = exp2f((sc[tmK][2] * scale + bb.z) * L2E);
            float e3 = exp2f((sc[tmK][3] * scale + bb.w) * L2E);
            sc[tmK][0] = e0; sc[tmK][1] = e1;
            sc[tmK][2] = e2; sc[tmK][3] = e3;
            s += (e0 + e1) + (e2 + e3);
        }
        s += __shfl_xor(s, 16);
        s += __shfl_xor(s, 32);
        float rs = 1.0f / s;
        #pragma unroll
        for (int tmK = 0; tmK < 4; ++tmK)
            pP[tmK][tmQ] = pk4(sc[tmK][0] * rs, sc[tmK][1] * rs,
                               sc[tmK][2] * rs, sc[tmK][3] * rs);
    }

    // ---- PV: K=16 mfma(A=pP, B=fV); D[q 4lg+r][d lr] ----
    f32x4 o[4][2];
    #pragma unroll
    for (int tmq = 0; tmq < 4; ++tmq)
        #pragma unroll
        for (int tn = 0; tn < 2; ++tn)
            o[tmq][tn] = (f32x4){0.f, 0.f, 0.f, 0.f};
    #pragma unroll
    for (int tmK = 0; tmK < 4; ++tmK)
        #pragma unroll
        for (int tmq = 0; tmq < 4; ++tmq)
            #pragma unroll
            for (int tn = 0; tn < 2; ++tn)
                o[tmq][tn] = MFMA16(pP[tmK][tmq], fV[tmK][tn], o[tmq][tn]);

    // ---- direct coalesced float4 stores (4 consecutive tokens per reg) ----
    #pragma unroll
    for (int tmq = 0; tmq < 4; ++tmq)
        #pragma unroll
        for (int tn = 0; tn < 2; ++tn) {
            int ch = 32 * w + 16 * tn + lr;
            int tok = 16 * tmq + 4 * lg;
            float4 ov;
            ov.x = o[tmq][tn][0];
            ov.y = o[tmq][tn][1];
            ov.z = o[tmq][tn][2];
            ov.w = o[tmq][tn][3];
            *(float4*)(out + xbase + (long)ch * 16384 + tok) = ov;
        }
}

extern "C" void kernel_launch(void* const* d_in, const int* in_sizes, int n_in,
                              void* d_out, int out_size, void* d_ws, size_t ws_size,
                              hipStream_t stream) {
    const float* x  = (const float*)d_in[0];
    const float* Wq = (const float*)d_in[1];
    const float* bq = (const float*)d_in[2];
    const float* Wk = (const float*)d_in[3];
    const float* bk = (const float*)d_in[4];
    const float* Wv = (const float*)d_in[5];
    const float* bv = (const float*)d_in[6];
    const float* Bb = (const float*)d_in[7];
    float* out = (float*)d_out;
    ushort* wbf = (ushort*)d_ws;   // 3 x 128x128 bf16 = 96 KB

    wconv<<<64, 256, 0, stream>>>(Wq, Wk, Wv, wbf);
    attn_win<<<4096, 256, 0, stream>>>(x, wbf, bq, bk, bv, Bb, out);
}